// Round 1
// baseline (2066.811 us; speedup 1.0000x reference)
//
#include <hip/hip_runtime.h>
#include <hip/hip_bf16.h>
#include <cstdint>

#define N_NODES   100000
#define N_EDGES   1600000
#define N_GRAPHS  128
#define HDIM      256
#define BN_EPS    1e-5f

// rows padded to GEMM tile (BM=128): 782*128
#define NROWS_PAD 100096

static __device__ __forceinline__ int imin(int a, int b) { return a < b ? a : b; }
static __device__ __forceinline__ int imax(int a, int b) { return a > b ? a : b; }

// ---------------------------------------------------------------- CSR build
__global__ void k_edge_count(const int* __restrict__ ei, int* __restrict__ cnt, int E) {
    int e = blockIdx.x * blockDim.x + threadIdx.x;
    if (e < E) atomicAdd(&cnt[ei[E + e]], 1);
}

__global__ __launch_bounds__(1024) void k_scan_sums(const int* __restrict__ cnt,
                                                    int* __restrict__ partials, int n) {
    __shared__ int sh[1024];
    int t = threadIdx.x;
    int i = blockIdx.x * 1024 + t;
    sh[t] = (i < n) ? cnt[i] : 0;
    __syncthreads();
    for (int off = 512; off > 0; off >>= 1) {
        if (t < off) sh[t] += sh[t + off];
        __syncthreads();
    }
    if (t == 0) partials[blockIdx.x] = sh[0];
}

__global__ void k_scan_offsets(int* partials, int nb) {
    if (blockIdx.x == 0 && threadIdx.x == 0) {
        int run = 0;
        for (int b = 0; b < nb; ++b) { int v = partials[b]; partials[b] = run; run += v; }
    }
}

__global__ __launch_bounds__(1024) void k_scan_write(const int* __restrict__ cnt,
                                                     const int* __restrict__ partials,
                                                     int* __restrict__ row_ptr,
                                                     int* __restrict__ cursor, int n) {
    __shared__ int sh[1024];
    int t = threadIdx.x;
    int i = blockIdx.x * 1024 + t;
    int v = (i < n) ? cnt[i] : 0;
    sh[t] = v;
    __syncthreads();
    for (int off = 1; off < 1024; off <<= 1) {
        int x = (t >= off) ? sh[t - off] : 0;
        __syncthreads();
        sh[t] += x;
        __syncthreads();
    }
    int excl = sh[t] - v + partials[blockIdx.x];
    if (i <= n) row_ptr[i] = excl;   // row_ptr[n] == E since cnt[j>=n] treated as 0
    if (i < n)  cursor[i]  = excl;
}

__global__ void k_fill(const int* __restrict__ ei, int* __restrict__ cursor,
                       int* __restrict__ csr_src, int E) {
    int e = blockIdx.x * blockDim.x + threadIdx.x;
    if (e < E) {
        int d = ei[E + e];
        int p = atomicAdd(&cursor[d], 1);
        csr_src[p] = ei[e];
    }
}

// ------------------------------------------------------------ aggregation
// z[i] = (sum_{e in-edges of i} h[src]) / max(deg,1) + h[i]
// one wave per node; lanes cover the feature dim (D/64 floats per lane)
template <int D>
__global__ __launch_bounds__(256) void k_aggregate(const float* __restrict__ h,
                                                   const int* __restrict__ row_ptr,
                                                   const int* __restrict__ csr_src,
                                                   float* __restrict__ z, int n) {
    int wid = blockIdx.x * 4 + (threadIdx.x >> 6);
    wid = __builtin_amdgcn_readfirstlane(wid);
    if (wid >= n) return;
    const int lane = threadIdx.x & 63;
    const int beg = row_ptr[wid];
    const int end = row_ptr[wid + 1];
    constexpr int V = D / 64;
    float acc[V];
#pragma unroll
    for (int j = 0; j < V; ++j) acc[j] = 0.f;
    const int col = lane * V;
    for (int e = beg; e < end; ++e) {
        int s = csr_src[e];
        const float* hp = h + (size_t)s * D + col;
        if constexpr (V == 4) {
            float4 v = *reinterpret_cast<const float4*>(hp);
            acc[0] += v.x; acc[1] += v.y; acc[2] += v.z; acc[3] += v.w;
        } else {
            float2 v = *reinterpret_cast<const float2*>(hp);
            acc[0] += v.x; acc[1] += v.y;
        }
    }
    const float inv = 1.0f / (float)imax(end - beg, 1);
    const float* hs = h + (size_t)wid * D + col;
    float* zp = z + (size_t)wid * D + col;
    if constexpr (V == 4) {
        float4 sv = *reinterpret_cast<const float4*>(hs);
        float4 o;
        o.x = acc[0] * inv + sv.x;
        o.y = acc[1] * inv + sv.y;
        o.z = acc[2] * inv + sv.z;
        o.w = acc[3] * inv + sv.w;
        *reinterpret_cast<float4*>(zp) = o;
    } else {
        float2 sv = *reinterpret_cast<const float2*>(hs);
        float2 o;
        o.x = acc[0] * inv + sv.x;
        o.y = acc[1] * inv + sv.y;
        *reinterpret_cast<float2*>(zp) = o;
    }
}

// ------------------------------------------------------------------- GEMM
// C[n,256] = relu(A[n,K] @ W[K,256] + bias). BM=128, BN=64, BK=32, 8x4 micro.
template <int K>
__global__ __launch_bounds__(256) void k_gemm_relu(const float* __restrict__ A,
                                                   const float* __restrict__ W,
                                                   const float* __restrict__ bias,
                                                   float* __restrict__ C, int n) {
    constexpr int BM = 128, BN = 64, BK = 32;
    __shared__ float As[BK][BM + 8];   // row stride 136 floats = 544 B (16B-mult)
    __shared__ float Ws[BK][BN + 4];   // row stride  68 floats = 272 B (16B-mult)
    const int tid = threadIdx.x;
    const int tx = tid & 15, ty = tid >> 4;
    const int row0 = blockIdx.x * BM;
    const int n0 = blockIdx.y * BN;

    float acc[8][4];
#pragma unroll
    for (int i = 0; i < 8; ++i)
#pragma unroll
        for (int j = 0; j < 4; ++j) acc[i][j] = 0.f;

    for (int k0 = 0; k0 < K; k0 += BK) {
        // A tile (BM x BK), stored transposed into LDS
#pragma unroll
        for (int p = 0; p < 4; ++p) {
            int id = p * 256 + tid;     // 0..1023
            int r  = id >> 3;           // 0..127
            int c4 = id & 7;            // 0..7
            int gr = imin(row0 + r, n - 1);
            float4 v = *reinterpret_cast<const float4*>(&A[(size_t)gr * K + k0 + c4 * 4]);
            As[c4 * 4 + 0][r] = v.x;
            As[c4 * 4 + 1][r] = v.y;
            As[c4 * 4 + 2][r] = v.z;
            As[c4 * 4 + 3][r] = v.w;
        }
        // W tile (BK x BN)
#pragma unroll
        for (int p = 0; p < 2; ++p) {
            int id = p * 256 + tid;     // 0..511
            int kk = id >> 4;           // 0..31
            int n4 = id & 15;           // 0..15
            float4 v = *reinterpret_cast<const float4*>(&W[(size_t)(k0 + kk) * HDIM + n0 + n4 * 4]);
            *reinterpret_cast<float4*>(&Ws[kk][n4 * 4]) = v;
        }
        __syncthreads();
#pragma unroll
        for (int kk = 0; kk < BK; ++kk) {
            const float4* ap = reinterpret_cast<const float4*>(&As[kk][ty * 8]);
            float4 a0 = ap[0], a1 = ap[1];
            float4 w0 = *reinterpret_cast<const float4*>(&Ws[kk][tx * 4]);
            float a[8] = {a0.x, a0.y, a0.z, a0.w, a1.x, a1.y, a1.z, a1.w};
            float w[4] = {w0.x, w0.y, w0.z, w0.w};
#pragma unroll
            for (int i = 0; i < 8; ++i)
#pragma unroll
                for (int j = 0; j < 4; ++j) acc[i][j] = fmaf(a[i], w[j], acc[i][j]);
        }
        __syncthreads();
    }
    float4 b4 = *reinterpret_cast<const float4*>(&bias[n0 + tx * 4]);
#pragma unroll
    for (int i = 0; i < 8; ++i) {
        int gr = row0 + ty * 8 + i;
        if (gr < n) {
            float4 o;
            o.x = fmaxf(acc[i][0] + b4.x, 0.f);
            o.y = fmaxf(acc[i][1] + b4.y, 0.f);
            o.z = fmaxf(acc[i][2] + b4.z, 0.f);
            o.w = fmaxf(acc[i][3] + b4.w, 0.f);
            *reinterpret_cast<float4*>(&C[(size_t)gr * HDIM + n0 + tx * 4]) = o;
        }
    }
}

// -------------------------------------------------------------------- BN
__global__ __launch_bounds__(256) void k_bn_stats(const float* __restrict__ h,
                                                  float* __restrict__ stats, int n) {
    int f = threadIdx.x;
    float s = 0.f, q = 0.f;
    for (int r = blockIdx.x; r < n; r += gridDim.x) {
        float v = h[(size_t)r * HDIM + f];
        s += v;
        q += v * v;
    }
    atomicAdd(&stats[f], s);
    atomicAdd(&stats[HDIM + f], q);
}

__global__ void k_bn_finalize(const float* __restrict__ stats, const float* __restrict__ g,
                              const float* __restrict__ be, float* __restrict__ st, int n) {
    int f = threadIdx.x;
    float mu = stats[f] / (float)n;
    float var = stats[HDIM + f] / (float)n - mu * mu;
    var = fmaxf(var, 0.f);
    float sc = g[f] * rsqrtf(var + BN_EPS);
    st[f] = sc;
    st[HDIM + f] = be[f] - mu * sc;
}

__global__ __launch_bounds__(256) void k_bn_apply(float* __restrict__ h,
                                                  const float* __restrict__ st, int n) {
    const int total = n * (HDIM / 4);
    const float4* s4 = reinterpret_cast<const float4*>(st);
    const float4* t4 = reinterpret_cast<const float4*>(st + HDIM);
    float4* h4 = reinterpret_cast<float4*>(h);
    for (int i = blockIdx.x * blockDim.x + threadIdx.x; i < total; i += gridDim.x * blockDim.x) {
        int c4 = i & 63;
        float4 v = h4[i];
        float4 s = s4[c4];
        float4 t = t4[c4];
        v.x = fmaf(s.x, v.x, t.x);
        v.y = fmaf(s.y, v.y, t.y);
        v.z = fmaf(s.z, v.z, t.z);
        v.w = fmaf(s.w, v.w, t.w);
        h4[i] = v;
    }
}

// --------------------------------------------------------------- pooling
// batch is sorted; fold layer-3 BN affine into the pooled sum.
__global__ __launch_bounds__(256) void k_pool(const float* __restrict__ h,
                                              const int* __restrict__ batch,
                                              const float* __restrict__ st,
                                              float* __restrict__ pooled, int n) {
    __shared__ int bsh[128];
    const int f = threadIdx.x;
    const int r0 = blockIdx.x * 128;
    const int cnt = imin(128, n - r0);
    if (cnt <= 0) return;
    if (f < cnt) bsh[f] = batch[r0 + f];
    __syncthreads();
    const float sc = st[f], tb = st[HDIM + f];
    float acc = 0.f;
    int cur = bsh[0];
    for (int i = 0; i < cnt; ++i) {
        int b = bsh[i];
        if (b != cur) {
            atomicAdd(&pooled[cur * HDIM + f], acc);
            acc = 0.f;
            cur = b;
        }
        acc = fmaf(sc, h[(size_t)(r0 + i) * HDIM + f], acc + tb);
    }
    atomicAdd(&pooled[cur * HDIM + f], acc);
}

// ------------------------------------------------------------------ head
__global__ __launch_bounds__(256) void k_head(const float* __restrict__ pooled,
                                              const float* __restrict__ w1,
                                              const float* __restrict__ b1,
                                              const float* __restrict__ w2,
                                              const float* __restrict__ b2,
                                              float* __restrict__ out) {
    __shared__ float p[HDIM];
    __shared__ float red[HDIM];
    const int g = blockIdx.x, j = threadIdx.x;
    p[j] = pooled[g * HDIM + j];
    __syncthreads();
    float a = b1[j];
    for (int k = 0; k < HDIM; ++k) a = fmaf(p[k], w1[k * HDIM + j], a);
    a = fmaxf(a, 0.f) * w2[j];
    red[j] = a;
    __syncthreads();
    for (int s = 128; s > 0; s >>= 1) {
        if (j < s) red[j] += red[j + s];
        __syncthreads();
    }
    if (j == 0) out[g] = red[0] + b2[0];
}

// ================================================================= launch
extern "C" void kernel_launch(void* const* d_in, const int* in_sizes, int n_in,
                              void* d_out, int out_size, void* d_ws, size_t ws_size,
                              hipStream_t stream) {
    const float* x     = (const float*)d_in[0];
    const int*   ei    = (const int*)d_in[1];
    const int*   batch = (const int*)d_in[2];
    const float* cw1[3] = {(const float*)d_in[3],  (const float*)d_in[9],  (const float*)d_in[15]};
    const float* cb1[3] = {(const float*)d_in[4],  (const float*)d_in[10], (const float*)d_in[16]};
    const float* cw2[3] = {(const float*)d_in[5],  (const float*)d_in[11], (const float*)d_in[17]};
    const float* cb2[3] = {(const float*)d_in[6],  (const float*)d_in[12], (const float*)d_in[18]};
    const float* cg [3] = {(const float*)d_in[7],  (const float*)d_in[13], (const float*)d_in[19]};
    const float* cbe[3] = {(const float*)d_in[8],  (const float*)d_in[14], (const float*)d_in[20]};
    const float* l1w = (const float*)d_in[21];
    const float* l1b = (const float*)d_in[22];
    const float* l2w = (const float*)d_in[23];
    const float* l2b = (const float*)d_in[24];
    float* out = (float*)d_out;

    const int N = N_NODES, E = N_EDGES;

    // ---- workspace carve (≈213 MB), everything 256B-aligned
    uintptr_t base = (uintptr_t)d_ws;
    auto alloc = [&](size_t bytes) {
        uintptr_t p = (base + 255) & ~(uintptr_t)255;
        base = p + bytes;
        return (void*)p;
    };
    float* bufA    = (float*)alloc((size_t)NROWS_PAD * HDIM * sizeof(float));
    float* bufB    = (float*)alloc((size_t)NROWS_PAD * HDIM * sizeof(float));
    int*   csr_src = (int*)alloc((size_t)E * sizeof(int));
    int*   cnt     = (int*)alloc((size_t)N * sizeof(int));
    int*   row_ptr = (int*)alloc((size_t)(N + 1) * sizeof(int));
    int*   cursor  = (int*)alloc((size_t)N * sizeof(int));
    int*   partials= (int*)alloc(256 * sizeof(int));
    float* stats   = (float*)alloc(2 * HDIM * sizeof(float));
    float* stbuf   = (float*)alloc(2 * HDIM * sizeof(float));
    float* pooled  = (float*)alloc((size_t)N_GRAPHS * HDIM * sizeof(float));

    // ---- CSR build (counting sort by dst)
    hipMemsetAsync(cnt, 0, (size_t)N * sizeof(int), stream);
    k_edge_count<<<(E + 255) / 256, 256, 0, stream>>>(ei, cnt, E);
    const int NB = (N + 1023) / 1024;  // 98 (covers index n for row_ptr[n])
    k_scan_sums<<<NB, 1024, 0, stream>>>(cnt, partials, N);
    k_scan_offsets<<<1, 64, 0, stream>>>(partials, NB);
    k_scan_write<<<NB, 1024, 0, stream>>>(cnt, partials, row_ptr, cursor, N);
    k_fill<<<(E + 255) / 256, 256, 0, stream>>>(ei, cursor, csr_src, E);

    const dim3 gemm_grid((N + 127) / 128, HDIM / 64);
    const int agg_grid = (N + 3) / 4;

    // ---- layer 1 (input x, d=128)
    k_aggregate<128><<<agg_grid, 256, 0, stream>>>(x, row_ptr, csr_src, bufA, N);
    k_gemm_relu<128><<<gemm_grid, 256, 0, stream>>>(bufA, cw1[0], cb1[0], bufB, N);
    k_gemm_relu<256><<<gemm_grid, 256, 0, stream>>>(bufB, cw2[0], cb2[0], bufA, N);
    hipMemsetAsync(stats, 0, 2 * HDIM * sizeof(float), stream);
    k_bn_stats<<<1024, 256, 0, stream>>>(bufA, stats, N);
    k_bn_finalize<<<1, 256, 0, stream>>>(stats, cg[0], cbe[0], stbuf, N);
    k_bn_apply<<<2048, 256, 0, stream>>>(bufA, stbuf, N);

    // ---- layer 2 (h in bufA, d=256)
    k_aggregate<256><<<agg_grid, 256, 0, stream>>>(bufA, row_ptr, csr_src, bufB, N);
    k_gemm_relu<256><<<gemm_grid, 256, 0, stream>>>(bufB, cw1[1], cb1[1], bufA, N);
    k_gemm_relu<256><<<gemm_grid, 256, 0, stream>>>(bufA, cw2[1], cb2[1], bufB, N);
    hipMemsetAsync(stats, 0, 2 * HDIM * sizeof(float), stream);
    k_bn_stats<<<1024, 256, 0, stream>>>(bufB, stats, N);
    k_bn_finalize<<<1, 256, 0, stream>>>(stats, cg[1], cbe[1], stbuf, N);
    k_bn_apply<<<2048, 256, 0, stream>>>(bufB, stbuf, N);

    // ---- layer 3 (h in bufB, d=256); BN folded into pooling
    k_aggregate<256><<<agg_grid, 256, 0, stream>>>(bufB, row_ptr, csr_src, bufA, N);
    k_gemm_relu<256><<<gemm_grid, 256, 0, stream>>>(bufA, cw1[2], cb1[2], bufB, N);
    k_gemm_relu<256><<<gemm_grid, 256, 0, stream>>>(bufB, cw2[2], cb2[2], bufA, N);
    hipMemsetAsync(stats, 0, 2 * HDIM * sizeof(float), stream);
    k_bn_stats<<<1024, 256, 0, stream>>>(bufA, stats, N);
    k_bn_finalize<<<1, 256, 0, stream>>>(stats, cg[2], cbe[2], stbuf, N);

    // ---- pool + head
    hipMemsetAsync(pooled, 0, (size_t)N_GRAPHS * HDIM * sizeof(float), stream);
    k_pool<<<(N + 127) / 128, 256, 0, stream>>>(bufA, batch, stbuf, pooled, N);
    k_head<<<N_GRAPHS, 256, 0, stream>>>(pooled, l1w, l1b, l2w, l2b, out);
}

// Round 2
// 1115.536 us; speedup vs baseline: 1.8528x; 1.8528x over previous
//
#include <hip/hip_runtime.h>
#include <hip/hip_bf16.h>
#include <cstdint>

#define N_NODES   100000
#define N_EDGES   1600000
#define N_GRAPHS  128
#define HDIM      256
#define BN_EPS    1e-5f
#define NROWS_PAD 100096

typedef __attribute__((ext_vector_type(8))) short bf16x8;
typedef __attribute__((ext_vector_type(4))) float f32x4;

static __device__ __forceinline__ int imin(int a, int b) { return a < b ? a : b; }
static __device__ __forceinline__ int imax(int a, int b) { return a > b ? a : b; }

static __device__ __forceinline__ float bl(unsigned u) { return __uint_as_float(u << 16); }
static __device__ __forceinline__ float bh(unsigned u) { return __uint_as_float(u & 0xffff0000u); }
static __device__ __forceinline__ unsigned short f2b(float f) {
    __hip_bfloat16 b = __float2bfloat16(f);
    return *(unsigned short*)&b;
}

static __device__ __forceinline__ void gload_lds16(void* ldsp, const void* gp) {
    __builtin_amdgcn_global_load_lds(
        (const __attribute__((address_space(1))) void*)gp,
        (__attribute__((address_space(3))) void*)ldsp, 16, 0, 0);
}

// ---------------------------------------------------------------- CSR build
__global__ void k_edge_count(const int* __restrict__ ei, int* __restrict__ cnt, int E) {
    int e = blockIdx.x * blockDim.x + threadIdx.x;
    if (e < E) atomicAdd(&cnt[ei[E + e]], 1);
}

__global__ __launch_bounds__(1024) void k_scan_sums(const int* __restrict__ cnt,
                                                    int* __restrict__ partials, int n) {
    __shared__ int sh[1024];
    int t = threadIdx.x;
    int i = blockIdx.x * 1024 + t;
    sh[t] = (i < n) ? cnt[i] : 0;
    __syncthreads();
    for (int off = 512; off > 0; off >>= 1) {
        if (t < off) sh[t] += sh[t + off];
        __syncthreads();
    }
    if (t == 0) partials[blockIdx.x] = sh[0];
}

__global__ void k_scan_offsets(int* partials, int nb) {
    if (blockIdx.x == 0 && threadIdx.x == 0) {
        int run = 0;
        for (int b = 0; b < nb; ++b) { int v = partials[b]; partials[b] = run; run += v; }
    }
}

__global__ __launch_bounds__(1024) void k_scan_write(const int* __restrict__ cnt,
                                                     const int* __restrict__ partials,
                                                     int* __restrict__ row_ptr,
                                                     int* __restrict__ cursor, int n) {
    __shared__ int sh[1024];
    int t = threadIdx.x;
    int i = blockIdx.x * 1024 + t;
    int v = (i < n) ? cnt[i] : 0;
    sh[t] = v;
    __syncthreads();
    for (int off = 1; off < 1024; off <<= 1) {
        int x = (t >= off) ? sh[t - off] : 0;
        __syncthreads();
        sh[t] += x;
        __syncthreads();
    }
    int excl = sh[t] - v + partials[blockIdx.x];
    if (i <= n) row_ptr[i] = excl;
    if (i < n)  cursor[i]  = excl;
}

__global__ void k_fill(const int* __restrict__ ei, int* __restrict__ cursor,
                       int* __restrict__ csr_src, int E) {
    int e = blockIdx.x * blockDim.x + threadIdx.x;
    if (e < E) {
        int d = ei[E + e];
        int p = atomicAdd(&cursor[d], 1);
        csr_src[p] = ei[e];
    }
}

// ---------------------------------------------------------------- casts/prep
__global__ void k_cast_x(const float* __restrict__ x, unsigned short* __restrict__ xb, int total4) {
    int i = blockIdx.x * blockDim.x + threadIdx.x;
    if (i < total4) {
        float4 v = reinterpret_cast<const float4*>(x)[i];
        uint2 o;
        o.x = (unsigned)f2b(v.x) | ((unsigned)f2b(v.y) << 16);
        o.y = (unsigned)f2b(v.z) | ((unsigned)f2b(v.w) << 16);
        reinterpret_cast<uint2*>(xb)[i] = o;
    }
}

// W[K][256] fp32 -> Wt[256][K] bf16 (LDS tile transpose)
__global__ __launch_bounds__(256) void k_prep_w(const float* __restrict__ w,
                                                unsigned short* __restrict__ wt, int K) {
    __shared__ float t[32][33];
    int kb = blockIdx.x * 32, nb = blockIdx.y * 32;
    int c = threadIdx.x & 31, r0 = threadIdx.x >> 5;
    for (int r = r0; r < 32; r += 8) t[r][c] = w[(size_t)(kb + r) * HDIM + nb + c];
    __syncthreads();
    for (int r = r0; r < 32; r += 8) wt[(size_t)(nb + r) * K + kb + c] = f2b(t[c][r]);
}

// ------------------------------------------------------------ aggregation
// z = mean_j h_j + h_i  (optionally with previous-layer BN folded:
//  z = sc*(mean_j h_j + h_i) + tb*(deg>0 ? 2 : 1))
template <int D>
__global__ __launch_bounds__(256) void k_aggregate_bf(const unsigned short* __restrict__ h,
                                                      const int* __restrict__ row_ptr,
                                                      const int* __restrict__ csr_src,
                                                      const float* __restrict__ st,
                                                      unsigned short* __restrict__ z, int n) {
    int wid = blockIdx.x * 4 + (threadIdx.x >> 6);
    wid = __builtin_amdgcn_readfirstlane(wid);
    if (wid >= n) return;
    const int lane = threadIdx.x & 63;
    const int beg = row_ptr[wid];
    const int end = row_ptr[wid + 1];
    constexpr int V = D / 64;          // bf16 per lane (4 or 2)
    const int col = lane * V;
    float acc[V];
#pragma unroll
    for (int j = 0; j < V; ++j) acc[j] = 0.f;

    for (int e = beg; e < end; ++e) {
        int s = csr_src[e];
        if constexpr (V == 4) {
            uint2 v = *reinterpret_cast<const uint2*>(h + (size_t)s * D + col);
            acc[0] += bl(v.x); acc[1] += bh(v.x);
            acc[2] += bl(v.y); acc[3] += bh(v.y);
        } else {
            unsigned v = *reinterpret_cast<const unsigned*>(h + (size_t)s * D + col);
            acc[0] += bl(v); acc[1] += bh(v);
        }
    }
    const float inv = 1.0f / (float)imax(end - beg, 1);
    float m[V];
    if constexpr (V == 4) {
        uint2 sv = *reinterpret_cast<const uint2*>(h + (size_t)wid * D + col);
        m[0] = acc[0] * inv + bl(sv.x); m[1] = acc[1] * inv + bh(sv.x);
        m[2] = acc[2] * inv + bl(sv.y); m[3] = acc[3] * inv + bh(sv.y);
    } else {
        unsigned sv = *reinterpret_cast<const unsigned*>(h + (size_t)wid * D + col);
        m[0] = acc[0] * inv + bl(sv); m[1] = acc[1] * inv + bh(sv);
    }
    if (st) {
        const float tbm = (end > beg) ? 2.f : 1.f;
#pragma unroll
        for (int j = 0; j < V; ++j) m[j] = st[col + j] * m[j] + tbm * st[HDIM + col + j];
    }
    if constexpr (V == 4) {
        uint2 o;
        o.x = (unsigned)f2b(m[0]) | ((unsigned)f2b(m[1]) << 16);
        o.y = (unsigned)f2b(m[2]) | ((unsigned)f2b(m[3]) << 16);
        *reinterpret_cast<uint2*>(z + (size_t)wid * D + col) = o;
    } else {
        unsigned o = (unsigned)f2b(m[0]) | ((unsigned)f2b(m[1]) << 16);
        *reinterpret_cast<unsigned*>(z + (size_t)wid * D + col) = o;
    }
}

// ------------------------------------------------------------------- GEMM
// C[n,256] = relu(A[n,K] @ W[K,256] + bias), A bf16 row-major, Wt = W^T bf16.
// 128x128 tile, 4 waves (2x2), wave tile 64x64, BK=64, mfma 16x16x32 bf16.
// LDS XOR-swizzle (16B slot ^= row&7) on both the gload source and ds_read.
template <int K>
__global__ __launch_bounds__(256, 2) void k_gemm_mfma(const unsigned short* __restrict__ A,
                                                      const unsigned short* __restrict__ Wt,
                                                      const float* __restrict__ bias,
                                                      unsigned short* __restrict__ C, int n) {
    constexpr int BK = 64;
    __shared__ unsigned char lds[2 * 128 * BK * 2];   // 16 KB A + 16 KB B
    unsigned char* Als = lds;
    unsigned char* Bls = lds + 128 * BK * 2;

    const int tid = threadIdx.x;
    const int lane = tid & 63;
    const int wv = tid >> 6;
    const int wm = wv >> 1, wn = wv & 1;
    const long row0 = (long)blockIdx.x * 128;
    const int n0 = blockIdx.y * 128;

    f32x4 acc[4][4];
#pragma unroll
    for (int m = 0; m < 4; ++m)
#pragma unroll
        for (int nn = 0; nn < 4; ++nn) acc[m][nn] = (f32x4){0.f, 0.f, 0.f, 0.f};

    const int srow = tid >> 3;      // 0..31 (row within 32-row group)
    const int sslot = tid & 7;      // 16B slot in LDS

    for (int k0 = 0; k0 < K; k0 += BK) {
        // stage A and B tiles: 1024 chunks of 16B each, chunk c = p*256 + tid.
        // LDS is linear; the global source slot is XOR-swizzled so that
        // LDS[row][s'] = G[row][s' ^ (row&7)].
#pragma unroll
        for (int p = 0; p < 4; ++p) {
            int r = p * 32 + srow;
            int gs = sslot ^ (r & 7);
            gload_lds16(Als + (p * 256 + wv * 64) * 16,
                        A + (row0 + r) * K + k0 + gs * 8);
            gload_lds16(Bls + (p * 256 + wv * 64) * 16,
                        Wt + (size_t)(n0 + r) * K + k0 + gs * 8);
        }
        __syncthreads();

        bf16x8 af[2][4], bfr[2][4];
#pragma unroll
        for (int kk = 0; kk < 2; ++kk) {
            int slot = kk * 4 + (lane >> 4);
#pragma unroll
            for (int m = 0; m < 4; ++m) {
                int r = wm * 64 + m * 16 + (lane & 15);
                af[kk][m] = *(const bf16x8*)(Als + r * 128 + ((slot ^ (r & 7)) * 16));
            }
#pragma unroll
            for (int nn = 0; nn < 4; ++nn) {
                int r = wn * 64 + nn * 16 + (lane & 15);
                bfr[kk][nn] = *(const bf16x8*)(Bls + r * 128 + ((slot ^ (r & 7)) * 16));
            }
        }
#pragma unroll
        for (int kk = 0; kk < 2; ++kk)
#pragma unroll
            for (int m = 0; m < 4; ++m)
#pragma unroll
                for (int nn = 0; nn < 4; ++nn)
                    acc[m][nn] = __builtin_amdgcn_mfma_f32_16x16x32_bf16(
                        af[kk][m], bfr[kk][nn], acc[m][nn], 0, 0, 0);
        __syncthreads();
    }

    const int cb = lane & 15, rb = lane >> 4;
#pragma unroll
    for (int nn = 0; nn < 4; ++nn) {
        int col = n0 + wn * 64 + nn * 16 + cb;
        float bv = bias[col];
#pragma unroll
        for (int m = 0; m < 4; ++m) {
            long grow = row0 + wm * 64 + m * 16 + rb * 4;
#pragma unroll
            for (int r = 0; r < 4; ++r) {
                if (grow + r < n) {
                    float v = fmaxf(acc[m][nn][r] + bv, 0.f);
                    C[(grow + r) * HDIM + col] = f2b(v);
                }
            }
        }
    }
}

// -------------------------------------------------------------------- BN
__global__ __launch_bounds__(256) void k_bn_stats_bf(const unsigned short* __restrict__ h,
                                                     float* __restrict__ stats, int n) {
    const int pr = threadIdx.x & 127;   // feature pair
    const int rs = threadIdx.x >> 7;    // row sub-stream
    float s0 = 0.f, s1 = 0.f, q0 = 0.f, q1 = 0.f;
    for (int r = blockIdx.x * 2 + rs; r < n; r += gridDim.x * 2) {
        unsigned u = *reinterpret_cast<const unsigned*>(h + (size_t)r * HDIM + pr * 2);
        float a = bl(u), b = bh(u);
        s0 += a; q0 += a * a;
        s1 += b; q1 += b * b;
    }
    atomicAdd(&stats[pr * 2],            s0);
    atomicAdd(&stats[pr * 2 + 1],        s1);
    atomicAdd(&stats[HDIM + pr * 2],     q0);
    atomicAdd(&stats[HDIM + pr * 2 + 1], q1);
}

__global__ void k_bn_finalize(const float* __restrict__ stats, const float* __restrict__ g,
                              const float* __restrict__ be, float* __restrict__ st, int n) {
    int f = threadIdx.x;
    float mu = stats[f] / (float)n;
    float var = stats[HDIM + f] / (float)n - mu * mu;
    var = fmaxf(var, 0.f);
    float sc = g[f] * rsqrtf(var + BN_EPS);
    st[f] = sc;
    st[HDIM + f] = be[f] - mu * sc;
}

// --------------------------------------------------------------- pooling
__global__ __launch_bounds__(128) void k_pool_bf(const unsigned short* __restrict__ h,
                                                 const int* __restrict__ batch,
                                                 const float* __restrict__ st,
                                                 float* __restrict__ pooled, int n) {
    __shared__ int bsh[128];
    const int p = threadIdx.x;          // feature pair 0..127
    const int r0 = blockIdx.x * 128;
    const int cnt = imin(128, n - r0);
    if (cnt <= 0) return;
    if (p < cnt) bsh[p] = batch[r0 + p];
    __syncthreads();
    const float sc0 = st[2 * p], sc1 = st[2 * p + 1];
    const float tb0 = st[HDIM + 2 * p], tb1 = st[HDIM + 2 * p + 1];
    float a0 = 0.f, a1 = 0.f;
    int cur = bsh[0];
    for (int i = 0; i < cnt; ++i) {
        int b = bsh[i];
        if (b != cur) {
            atomicAdd(&pooled[cur * HDIM + 2 * p], a0);
            atomicAdd(&pooled[cur * HDIM + 2 * p + 1], a1);
            a0 = a1 = 0.f;
            cur = b;
        }
        unsigned u = *reinterpret_cast<const unsigned*>(h + (size_t)(r0 + i) * HDIM + 2 * p);
        a0 += fmaf(sc0, bl(u), tb0);
        a1 += fmaf(sc1, bh(u), tb1);
    }
    atomicAdd(&pooled[cur * HDIM + 2 * p], a0);
    atomicAdd(&pooled[cur * HDIM + 2 * p + 1], a1);
}

// ------------------------------------------------------------------ head
__global__ __launch_bounds__(256) void k_head(const float* __restrict__ pooled,
                                              const float* __restrict__ w1,
                                              const float* __restrict__ b1,
                                              const float* __restrict__ w2,
                                              const float* __restrict__ b2,
                                              float* __restrict__ out) {
    __shared__ float p[HDIM];
    __shared__ float red[HDIM];
    const int g = blockIdx.x, j = threadIdx.x;
    p[j] = pooled[g * HDIM + j];
    __syncthreads();
    float a = b1[j];
    for (int k = 0; k < HDIM; ++k) a = fmaf(p[k], w1[k * HDIM + j], a);
    a = fmaxf(a, 0.f) * w2[j];
    red[j] = a;
    __syncthreads();
    for (int s = 128; s > 0; s >>= 1) {
        if (j < s) red[j] += red[j + s];
        __syncthreads();
    }
    if (j == 0) out[g] = red[0] + b2[0];
}

// ================================================================= launch
extern "C" void kernel_launch(void* const* d_in, const int* in_sizes, int n_in,
                              void* d_out, int out_size, void* d_ws, size_t ws_size,
                              hipStream_t stream) {
    const float* x     = (const float*)d_in[0];
    const int*   ei    = (const int*)d_in[1];
    const int*   batch = (const int*)d_in[2];
    const float* cw1[3] = {(const float*)d_in[3],  (const float*)d_in[9],  (const float*)d_in[15]};
    const float* cb1[3] = {(const float*)d_in[4],  (const float*)d_in[10], (const float*)d_in[16]};
    const float* cw2[3] = {(const float*)d_in[5],  (const float*)d_in[11], (const float*)d_in[17]};
    const float* cb2[3] = {(const float*)d_in[6],  (const float*)d_in[12], (const float*)d_in[18]};
    const float* cg [3] = {(const float*)d_in[7],  (const float*)d_in[13], (const float*)d_in[19]};
    const float* cbe[3] = {(const float*)d_in[8],  (const float*)d_in[14], (const float*)d_in[20]};
    const float* l1w = (const float*)d_in[21];
    const float* l1b = (const float*)d_in[22];
    const float* l2w = (const float*)d_in[23];
    const float* l2b = (const float*)d_in[24];
    float* out = (float*)d_out;

    const int N = N_NODES, E = N_EDGES;

    uintptr_t base = (uintptr_t)d_ws;
    auto alloc = [&](size_t bytes) {
        uintptr_t p = (base + 255) & ~(uintptr_t)255;
        base = p + bytes;
        return (void*)p;
    };
    unsigned short* xb = (unsigned short*)alloc((size_t)N_NODES * 128 * 2);
    unsigned short* B0 = (unsigned short*)alloc((size_t)NROWS_PAD * HDIM * 2);
    unsigned short* B1 = (unsigned short*)alloc((size_t)NROWS_PAD * HDIM * 2);
    unsigned short* B2 = (unsigned short*)alloc((size_t)NROWS_PAD * HDIM * 2);
    unsigned short* wt[6];
    for (int i = 0; i < 6; ++i) wt[i] = (unsigned short*)alloc((size_t)HDIM * HDIM * 2);
    int*   csr_src = (int*)alloc((size_t)E * sizeof(int));
    int*   cnt     = (int*)alloc((size_t)N * sizeof(int));
    int*   row_ptr = (int*)alloc((size_t)(N + 1) * sizeof(int));
    int*   cursor  = (int*)alloc((size_t)N * sizeof(int));
    int*   partials= (int*)alloc(256 * sizeof(int));
    float* stats   = (float*)alloc(2 * HDIM * sizeof(float));
    float* st      = (float*)alloc(2 * HDIM * sizeof(float));
    float* pooled  = (float*)alloc((size_t)N_GRAPHS * HDIM * sizeof(float));

    // ---- CSR build
    hipMemsetAsync(cnt, 0, (size_t)N * sizeof(int), stream);
    k_edge_count<<<(E + 255) / 256, 256, 0, stream>>>(ei, cnt, E);
    const int NB = (N + 1023) / 1024;
    k_scan_sums<<<NB, 1024, 0, stream>>>(cnt, partials, N);
    k_scan_offsets<<<1, 64, 0, stream>>>(partials, NB);
    k_scan_write<<<NB, 1024, 0, stream>>>(cnt, partials, row_ptr, cursor, N);
    k_fill<<<(E + 255) / 256, 256, 0, stream>>>(ei, cursor, csr_src, E);

    // ---- weight prep + x cast
    k_cast_x<<<(N * 128 / 4 + 255) / 256, 256, 0, stream>>>(x, xb, N * 128 / 4);
    const float* ws_[6] = {cw1[0], cw2[0], cw1[1], cw2[1], cw1[2], cw2[2]};
    const int    wk_[6] = {128, 256, 256, 256, 256, 256};
    for (int i = 0; i < 6; ++i)
        k_prep_w<<<dim3(wk_[i] / 32, 8), 256, 0, stream>>>(ws_[i], wt[i], wk_[i]);

    const int agg_grid = (N + 3) / 4;
    const dim3 gemm_grid((N + 127) / 128, 2);

    // ---- layer 1
    k_aggregate_bf<128><<<agg_grid, 256, 0, stream>>>(xb, row_ptr, csr_src, nullptr, B0, N);
    k_gemm_mfma<128><<<gemm_grid, 256, 0, stream>>>(B0, wt[0], cb1[0], B1, N);
    k_gemm_mfma<256><<<gemm_grid, 256, 0, stream>>>(B1, wt[1], cb2[0], B2, N);
    hipMemsetAsync(stats, 0, 2 * HDIM * sizeof(float), stream);
    k_bn_stats_bf<<<512, 256, 0, stream>>>(B2, stats, N);
    k_bn_finalize<<<1, 256, 0, stream>>>(stats, cg[0], cbe[0], st, N);

    // ---- layer 2 (BN of layer 1 folded into aggregation)
    k_aggregate_bf<256><<<agg_grid, 256, 0, stream>>>(B2, row_ptr, csr_src, st, B0, N);
    k_gemm_mfma<256><<<gemm_grid, 256, 0, stream>>>(B0, wt[2], cb1[1], B1, N);
    k_gemm_mfma<256><<<gemm_grid, 256, 0, stream>>>(B1, wt[3], cb2[1], B0, N);
    hipMemsetAsync(stats, 0, 2 * HDIM * sizeof(float), stream);
    k_bn_stats_bf<<<512, 256, 0, stream>>>(B0, stats, N);
    k_bn_finalize<<<1, 256, 0, stream>>>(stats, cg[1], cbe[1], st, N);

    // ---- layer 3
    k_aggregate_bf<256><<<agg_grid, 256, 0, stream>>>(B0, row_ptr, csr_src, st, B1, N);
    k_gemm_mfma<256><<<gemm_grid, 256, 0, stream>>>(B1, wt[4], cb1[2], B2, N);
    k_gemm_mfma<256><<<gemm_grid, 256, 0, stream>>>(B2, wt[5], cb2[2], B1, N);
    hipMemsetAsync(stats, 0, 2 * HDIM * sizeof(float), stream);
    k_bn_stats_bf<<<512, 256, 0, stream>>>(B1, stats, N);
    k_bn_finalize<<<1, 256, 0, stream>>>(stats, cg[2], cbe[2], st, N);

    // ---- pool (layer-3 BN folded) + head
    hipMemsetAsync(pooled, 0, (size_t)N_GRAPHS * HDIM * sizeof(float), stream);
    k_pool_bf<<<(N + 127) / 128, 128, 0, stream>>>(B1, batch, st, pooled, N);
    k_head<<<N_GRAPHS, 256, 0, stream>>>(pooled, l1w, l1b, l2w, l2b, out);
}

// Round 3
// 786.810 us; speedup vs baseline: 2.6268x; 1.4178x over previous
//
#include <hip/hip_runtime.h>
#include <hip/hip_bf16.h>
#include <cstdint>

#define N_NODES   100000
#define N_EDGES   1600000
#define N_GRAPHS  128
#define HDIM      256
#define BN_EPS    1e-5f
#define NROWS_PAD 100096
#define NBUCK     782          // ceil(N/128)
#define EPB       8192         // edges per block, bucket passes
#define CAP       3584         // max edges per bucket (mean 2046, sd ~45)

typedef _Float16 f16;
typedef __attribute__((ext_vector_type(8))) _Float16 f16x8;
typedef __attribute__((ext_vector_type(4))) float f32x4;

static __device__ __forceinline__ int imin(int a, int b) { return a < b ? a : b; }
static __device__ __forceinline__ int imax(int a, int b) { return a > b ? a : b; }

static __device__ __forceinline__ float h2f(unsigned short s) {
    return (float)__builtin_bit_cast(f16, s);
}
static __device__ __forceinline__ float hlo(unsigned u) { return h2f((unsigned short)(u & 0xffff)); }
static __device__ __forceinline__ float hhi(unsigned u) { return h2f((unsigned short)(u >> 16)); }
static __device__ __forceinline__ unsigned short f2h(float f) {
    return __builtin_bit_cast(unsigned short, (f16)f);
}
static __device__ __forceinline__ unsigned pk2(float a, float b) {
    return (unsigned)f2h(a) | ((unsigned)f2h(b) << 16);
}

static __device__ __forceinline__ void gload_lds16(void* ldsp, const void* gp) {
    __builtin_amdgcn_global_load_lds(
        (const __attribute__((address_space(1))) void*)gp,
        (__attribute__((address_space(3))) void*)ldsp, 16, 0, 0);
}

// ---------------------------------------------------- CSR build (bucketed)
__global__ __launch_bounds__(256) void k_bucket_count(const int* __restrict__ ei,
                                                      int* __restrict__ bcnt, int E) {
    __shared__ int h[NBUCK];
    for (int i = threadIdx.x; i < NBUCK; i += 256) h[i] = 0;
    __syncthreads();
    const int e0 = blockIdx.x * EPB;
    const int e1 = imin(e0 + EPB, E);
    for (int e = e0 + threadIdx.x; e < e1; e += 256)
        atomicAdd(&h[ei[E + e] >> 7], 1);
    __syncthreads();
    for (int i = threadIdx.x; i < NBUCK; i += 256)
        if (h[i]) atomicAdd(&bcnt[i], h[i]);
}

__global__ __launch_bounds__(1024) void k_bucket_scan(const int* __restrict__ bcnt,
                                                      int* __restrict__ bbase,
                                                      int* __restrict__ bcur) {
    __shared__ int sh[1024];
    const int t = threadIdx.x;
    const int v = (t < NBUCK) ? bcnt[t] : 0;
    sh[t] = v;
    __syncthreads();
    for (int off = 1; off < 1024; off <<= 1) {
        int x = (t >= off) ? sh[t - off] : 0;
        __syncthreads();
        sh[t] += x;
        __syncthreads();
    }
    const int excl = sh[t] - v;
    if (t <= NBUCK) bbase[t] = excl;   // bbase[NBUCK] == E
    if (t < NBUCK)  bcur[t]  = excl;
}

__global__ __launch_bounds__(256) void k_bucket_scatter(const int* __restrict__ ei,
                                                        int* __restrict__ bcur,
                                                        unsigned* __restrict__ bpack, int E) {
    __shared__ int h[NBUCK];
    __shared__ int base[NBUCK];
    for (int i = threadIdx.x; i < NBUCK; i += 256) h[i] = 0;
    __syncthreads();
    const int e0 = blockIdx.x * EPB;
    const int e1 = imin(e0 + EPB, E);
    for (int e = e0 + threadIdx.x; e < e1; e += 256)
        atomicAdd(&h[ei[E + e] >> 7], 1);
    __syncthreads();
    for (int i = threadIdx.x; i < NBUCK; i += 256) {
        int c = h[i];
        base[i] = c ? atomicAdd(&bcur[i], c) : 0;
        h[i] = 0;                       // reuse as block-local cursor
    }
    __syncthreads();
    for (int e = e0 + threadIdx.x; e < e1; e += 256) {
        int d = ei[E + e];
        int b = d >> 7;
        int p = base[b] + atomicAdd(&h[b], 1);
        bpack[p] = ((unsigned)(d & 127) << 17) | (unsigned)ei[e];
    }
}

__global__ __launch_bounds__(256) void k_bucket_sort(const unsigned* __restrict__ bpack,
                                                     const int* __restrict__ bbase,
                                                     int* __restrict__ csr_src,
                                                     int* __restrict__ row_ptr, int n) {
    __shared__ unsigned arr[CAP];
    __shared__ int sorted[CAP];
    __shared__ int hist[128], cur[128];
    const int b = blockIdx.x;
    const int t = threadIdx.x;
    const int lo = bbase[b];
    const int m = imin(bbase[b + 1] - lo, CAP);
    if (t < 128) hist[t] = 0;
    __syncthreads();
    for (int j = t; j < m; j += 256) {
        unsigned p = bpack[lo + j];
        arr[j] = p;
        atomicAdd(&hist[p >> 17], 1);
    }
    __syncthreads();
    if (t < 128) cur[t] = hist[t];
    __syncthreads();
    for (int off = 1; off < 128; off <<= 1) {
        int x = 0;
        if (t < 128 && t >= off) x = cur[t - off];
        __syncthreads();
        if (t < 128) cur[t] += x;
        __syncthreads();
    }
    if (t < 128) {
        int excl = cur[t] - hist[t];
        int node = b * 128 + t;
        if (node < n) row_ptr[node] = lo + excl;
        cur[t] = excl;
    }
    if (b == NBUCK - 1 && t == 0) row_ptr[n] = bbase[NBUCK];
    __syncthreads();
    for (int j = t; j < m; j += 256) {
        unsigned p = arr[j];
        int pos = atomicAdd(&cur[p >> 17], 1);
        sorted[pos] = (int)(p & 0x1ffff);
    }
    __syncthreads();
    for (int j = t; j < m; j += 256) csr_src[lo + j] = sorted[j];
}

// ---------------------------------------------------------------- casts/prep
__global__ void k_cast_x(const float* __restrict__ x, unsigned short* __restrict__ xh, int total4) {
    int i = blockIdx.x * blockDim.x + threadIdx.x;
    if (i < total4) {
        float4 v = reinterpret_cast<const float4*>(x)[i];
        uint2 o;
        o.x = pk2(v.x, v.y);
        o.y = pk2(v.z, v.w);
        reinterpret_cast<uint2*>(xh)[i] = o;
    }
}

// W[K][256] fp32 -> Wt[256][K] f16 (LDS tile transpose)
__global__ __launch_bounds__(256) void k_prep_w(const float* __restrict__ w,
                                                unsigned short* __restrict__ wt, int K) {
    __shared__ float t[32][33];
    int kb = blockIdx.x * 32, nb = blockIdx.y * 32;
    int c = threadIdx.x & 31, r0 = threadIdx.x >> 5;
    for (int r = r0; r < 32; r += 8) t[r][c] = w[(size_t)(kb + r) * HDIM + nb + c];
    __syncthreads();
    for (int r = r0; r < 32; r += 8) wt[(size_t)(nb + r) * K + kb + c] = f2h(t[c][r]);
}

// ------------------------------------------------------------ aggregation
// z = mean_j h_j + h_i, optionally with previous-layer BN folded:
//   z = sc*(mean + self) + tb*(deg>0 ? 2 : 1)
template <int D>
__global__ __launch_bounds__(256) void k_aggregate_f16(const unsigned short* __restrict__ h,
                                                       const int* __restrict__ row_ptr,
                                                       const int* __restrict__ csr_src,
                                                       const float* __restrict__ st,
                                                       unsigned short* __restrict__ z, int n) {
    int wid = blockIdx.x * 4 + (threadIdx.x >> 6);
    wid = __builtin_amdgcn_readfirstlane(wid);
    if (wid >= n) return;
    const int lane = threadIdx.x & 63;
    const int beg = row_ptr[wid];
    const int end = row_ptr[wid + 1];
    constexpr int V = D / 64;          // f16 per lane: 4 (D=256) or 2 (D=128)
    const int col = lane * V;
    float acc[V];
#pragma unroll
    for (int j = 0; j < V; ++j) acc[j] = 0.f;

    int e = beg;
    for (; e + 4 <= end; e += 4) {
        int s0 = csr_src[e], s1 = csr_src[e + 1], s2 = csr_src[e + 2], s3 = csr_src[e + 3];
        if constexpr (V == 4) {
            uint2 v0 = *reinterpret_cast<const uint2*>(h + (size_t)s0 * D + col);
            uint2 v1 = *reinterpret_cast<const uint2*>(h + (size_t)s1 * D + col);
            uint2 v2 = *reinterpret_cast<const uint2*>(h + (size_t)s2 * D + col);
            uint2 v3 = *reinterpret_cast<const uint2*>(h + (size_t)s3 * D + col);
            acc[0] += hlo(v0.x) + hlo(v1.x) + hlo(v2.x) + hlo(v3.x);
            acc[1] += hhi(v0.x) + hhi(v1.x) + hhi(v2.x) + hhi(v3.x);
            acc[2] += hlo(v0.y) + hlo(v1.y) + hlo(v2.y) + hlo(v3.y);
            acc[3] += hhi(v0.y) + hhi(v1.y) + hhi(v2.y) + hhi(v3.y);
        } else {
            unsigned v0 = *reinterpret_cast<const unsigned*>(h + (size_t)s0 * D + col);
            unsigned v1 = *reinterpret_cast<const unsigned*>(h + (size_t)s1 * D + col);
            unsigned v2 = *reinterpret_cast<const unsigned*>(h + (size_t)s2 * D + col);
            unsigned v3 = *reinterpret_cast<const unsigned*>(h + (size_t)s3 * D + col);
            acc[0] += hlo(v0) + hlo(v1) + hlo(v2) + hlo(v3);
            acc[1] += hhi(v0) + hhi(v1) + hhi(v2) + hhi(v3);
        }
    }
    for (; e < end; ++e) {
        int s = csr_src[e];
        if constexpr (V == 4) {
            uint2 v = *reinterpret_cast<const uint2*>(h + (size_t)s * D + col);
            acc[0] += hlo(v.x); acc[1] += hhi(v.x);
            acc[2] += hlo(v.y); acc[3] += hhi(v.y);
        } else {
            unsigned v = *reinterpret_cast<const unsigned*>(h + (size_t)s * D + col);
            acc[0] += hlo(v); acc[1] += hhi(v);
        }
    }
    const float inv = 1.0f / (float)imax(end - beg, 1);
    float m[V];
    if constexpr (V == 4) {
        uint2 sv = *reinterpret_cast<const uint2*>(h + (size_t)wid * D + col);
        m[0] = acc[0] * inv + hlo(sv.x); m[1] = acc[1] * inv + hhi(sv.x);
        m[2] = acc[2] * inv + hlo(sv.y); m[3] = acc[3] * inv + hhi(sv.y);
    } else {
        unsigned sv = *reinterpret_cast<const unsigned*>(h + (size_t)wid * D + col);
        m[0] = acc[0] * inv + hlo(sv); m[1] = acc[1] * inv + hhi(sv);
    }
    if (st) {
        const float tbm = (end > beg) ? 2.f : 1.f;
#pragma unroll
        for (int j = 0; j < V; ++j) m[j] = st[col + j] * m[j] + tbm * st[HDIM + col + j];
    }
    if constexpr (V == 4) {
        uint2 o;
        o.x = pk2(m[0], m[1]);
        o.y = pk2(m[2], m[3]);
        *reinterpret_cast<uint2*>(z + (size_t)wid * D + col) = o;
    } else {
        *reinterpret_cast<unsigned*>(z + (size_t)wid * D + col) = pk2(m[0], m[1]);
    }
}

// ------------------------------------------------------------------- GEMM
// C[n,256] = relu(A[n,K] @ W + bias), A f16 row-major, Wt = W^T f16.
// 128x128 tile, 4 waves (2x2), wave tile 64x64, BK=64, mfma 16x16x32 f16.
// XOR-swizzle: LDS linear dest, pre-swizzled global source, swizzled ds_read.
// STATS: fused BN sum/sumsq accumulation (per-column, guarded to rows < n).
template <int K, bool STATS>
__global__ __launch_bounds__(256, 2) void k_gemm_mfma(const unsigned short* __restrict__ A,
                                                      const unsigned short* __restrict__ Wt,
                                                      const float* __restrict__ bias,
                                                      unsigned short* __restrict__ C,
                                                      float* __restrict__ stats, int n) {
    constexpr int BK = 64;
    __shared__ unsigned char lds[2 * 128 * BK * 2];   // 16 KB A + 16 KB B
    __shared__ float ssum[128], ssq[128];
    unsigned char* Als = lds;
    unsigned char* Bls = lds + 128 * BK * 2;

    const int tid = threadIdx.x;
    const int lane = tid & 63;
    const int wv = tid >> 6;
    const int wm = wv >> 1, wn = wv & 1;
    const long row0 = (long)blockIdx.x * 128;
    const int n0 = blockIdx.y * 128;

    if constexpr (STATS) {
        if (tid < 128) { ssum[tid] = 0.f; ssq[tid] = 0.f; }
    }

    f32x4 acc[4][4];
#pragma unroll
    for (int m = 0; m < 4; ++m)
#pragma unroll
        for (int nn = 0; nn < 4; ++nn) acc[m][nn] = (f32x4){0.f, 0.f, 0.f, 0.f};

    const int srow = tid >> 3;      // 0..31
    const int sslot = tid & 7;      // 16B slot

    for (int k0 = 0; k0 < K; k0 += BK) {
#pragma unroll
        for (int p = 0; p < 4; ++p) {
            int r = p * 32 + srow;
            int gs = sslot ^ (r & 7);
            gload_lds16(Als + (p * 256 + wv * 64) * 16,
                        A + (row0 + r) * K + k0 + gs * 8);
            gload_lds16(Bls + (p * 256 + wv * 64) * 16,
                        Wt + (size_t)(n0 + r) * K + k0 + gs * 8);
        }
        __syncthreads();

        f16x8 af[2][4], bfr[2][4];
#pragma unroll
        for (int kk = 0; kk < 2; ++kk) {
            int slot = kk * 4 + (lane >> 4);
#pragma unroll
            for (int m = 0; m < 4; ++m) {
                int r = wm * 64 + m * 16 + (lane & 15);
                af[kk][m] = *(const f16x8*)(Als + r * 128 + ((slot ^ (r & 7)) * 16));
            }
#pragma unroll
            for (int nn = 0; nn < 4; ++nn) {
                int r = wn * 64 + nn * 16 + (lane & 15);
                bfr[kk][nn] = *(const f16x8*)(Bls + r * 128 + ((slot ^ (r & 7)) * 16));
            }
        }
#pragma unroll
        for (int kk = 0; kk < 2; ++kk)
#pragma unroll
            for (int m = 0; m < 4; ++m)
#pragma unroll
                for (int nn = 0; nn < 4; ++nn)
                    acc[m][nn] = __builtin_amdgcn_mfma_f32_16x16x32_f16(
                        af[kk][m], bfr[kk][nn], acc[m][nn], 0, 0, 0);
        __syncthreads();
    }

    const int cb = lane & 15, rb = lane >> 4;
#pragma unroll
    for (int nn = 0; nn < 4; ++nn) {
        const int coll = wn * 64 + nn * 16 + cb;
        const int col = n0 + coll;
        const float bv = bias[col];
        float lsum = 0.f, lsq = 0.f;
#pragma unroll
        for (int m = 0; m < 4; ++m) {
            long grow = row0 + wm * 64 + m * 16 + rb * 4;
#pragma unroll
            for (int r = 0; r < 4; ++r) {
                if (grow + r < n) {
                    float v = fmaxf(acc[m][nn][r] + bv, 0.f);
                    C[(grow + r) * HDIM + col] = f2h(v);
                    if constexpr (STATS) { lsum += v; lsq += v * v; }
                }
            }
        }
        if constexpr (STATS) {
            atomicAdd(&ssum[coll], lsum);
            atomicAdd(&ssq[coll], lsq);
        }
    }
    if constexpr (STATS) {
        __syncthreads();
        if (tid < 128) {
            atomicAdd(&stats[n0 + tid], ssum[tid]);
            atomicAdd(&stats[HDIM + n0 + tid], ssq[tid]);
        }
    }
}

// -------------------------------------------------------------------- BN
__global__ void k_bn_finalize(const float* __restrict__ stats, const float* __restrict__ g,
                              const float* __restrict__ be, float* __restrict__ st, int n) {
    int f = threadIdx.x;
    float mu = stats[f] / (float)n;
    float var = stats[HDIM + f] / (float)n - mu * mu;
    var = fmaxf(var, 0.f);
    float sc = g[f] * rsqrtf(var + BN_EPS);
    st[f] = sc;
    st[HDIM + f] = be[f] - mu * sc;
}

// --------------------------------------------------------------- pooling
__global__ __launch_bounds__(128) void k_pool_f16(const unsigned short* __restrict__ h,
                                                  const int* __restrict__ batch,
                                                  const float* __restrict__ st,
                                                  float* __restrict__ pooled, int n) {
    __shared__ int bsh[128];
    const int p = threadIdx.x;          // feature pair 0..127
    const int r0 = blockIdx.x * 128;
    const int cnt = imin(128, n - r0);
    if (cnt <= 0) return;
    if (p < cnt) bsh[p] = batch[r0 + p];
    __syncthreads();
    const float sc0 = st[2 * p], sc1 = st[2 * p + 1];
    const float tb0 = st[HDIM + 2 * p], tb1 = st[HDIM + 2 * p + 1];
    float a0 = 0.f, a1 = 0.f;
    int cur = bsh[0];
    for (int i = 0; i < cnt; ++i) {
        int b = bsh[i];
        if (b != cur) {
            atomicAdd(&pooled[cur * HDIM + 2 * p], a0);
            atomicAdd(&pooled[cur * HDIM + 2 * p + 1], a1);
            a0 = a1 = 0.f;
            cur = b;
        }
        unsigned u = *reinterpret_cast<const unsigned*>(h + (size_t)(r0 + i) * HDIM + 2 * p);
        a0 += fmaf(sc0, hlo(u), tb0);
        a1 += fmaf(sc1, hhi(u), tb1);
    }
    atomicAdd(&pooled[cur * HDIM + 2 * p], a0);
    atomicAdd(&pooled[cur * HDIM + 2 * p + 1], a1);
}

// ------------------------------------------------------------------ head
__global__ __launch_bounds__(256) void k_head(const float* __restrict__ pooled,
                                              const float* __restrict__ w1,
                                              const float* __restrict__ b1,
                                              const float* __restrict__ w2,
                                              const float* __restrict__ b2,
                                              float* __restrict__ out) {
    __shared__ float p[HDIM];
    __shared__ float red[HDIM];
    const int g = blockIdx.x, j = threadIdx.x;
    p[j] = pooled[g * HDIM + j];
    __syncthreads();
    float a = b1[j];
    for (int k = 0; k < HDIM; ++k) a = fmaf(p[k], w1[k * HDIM + j], a);
    a = fmaxf(a, 0.f) * w2[j];
    red[j] = a;
    __syncthreads();
    for (int s = 128; s > 0; s >>= 1) {
        if (j < s) red[j] += red[j + s];
        __syncthreads();
    }
    if (j == 0) out[g] = red[0] + b2[0];
}

// ================================================================= launch
extern "C" void kernel_launch(void* const* d_in, const int* in_sizes, int n_in,
                              void* d_out, int out_size, void* d_ws, size_t ws_size,
                              hipStream_t stream) {
    const float* x     = (const float*)d_in[0];
    const int*   ei    = (const int*)d_in[1];
    const int*   batch = (const int*)d_in[2];
    const float* cw1[3] = {(const float*)d_in[3],  (const float*)d_in[9],  (const float*)d_in[15]};
    const float* cb1[3] = {(const float*)d_in[4],  (const float*)d_in[10], (const float*)d_in[16]};
    const float* cw2[3] = {(const float*)d_in[5],  (const float*)d_in[11], (const float*)d_in[17]};
    const float* cb2[3] = {(const float*)d_in[6],  (const float*)d_in[12], (const float*)d_in[18]};
    const float* cg [3] = {(const float*)d_in[7],  (const float*)d_in[13], (const float*)d_in[19]};
    const float* cbe[3] = {(const float*)d_in[8],  (const float*)d_in[14], (const float*)d_in[20]};
    const float* l1w = (const float*)d_in[21];
    const float* l1b = (const float*)d_in[22];
    const float* l2w = (const float*)d_in[23];
    const float* l2b = (const float*)d_in[24];
    float* out = (float*)d_out;

    const int N = N_NODES, E = N_EDGES;

    uintptr_t base = (uintptr_t)d_ws;
    auto alloc = [&](size_t bytes) {
        uintptr_t p = (base + 255) & ~(uintptr_t)255;
        base = p + bytes;
        return (void*)p;
    };
    unsigned short* xh = (unsigned short*)alloc((size_t)N_NODES * 128 * 2);
    unsigned short* B0 = (unsigned short*)alloc((size_t)NROWS_PAD * HDIM * 2);
    unsigned short* B1 = (unsigned short*)alloc((size_t)NROWS_PAD * HDIM * 2);
    unsigned short* B2 = (unsigned short*)alloc((size_t)NROWS_PAD * HDIM * 2);
    unsigned short* wt[6];
    for (int i = 0; i < 6; ++i) wt[i] = (unsigned short*)alloc((size_t)HDIM * HDIM * 2);
    unsigned* bpack = (unsigned*)alloc((size_t)E * sizeof(unsigned));
    int*   csr_src  = (int*)alloc((size_t)E * sizeof(int));
    int*   bcnt     = (int*)alloc((size_t)NBUCK * sizeof(int));
    int*   bbase    = (int*)alloc((size_t)(NBUCK + 1) * sizeof(int));
    int*   bcur     = (int*)alloc((size_t)NBUCK * sizeof(int));
    int*   row_ptr  = (int*)alloc((size_t)(N + 1) * sizeof(int));
    float* stats    = (float*)alloc(2 * HDIM * sizeof(float));
    float* st       = (float*)alloc(2 * HDIM * sizeof(float));
    float* pooled   = (float*)alloc((size_t)N_GRAPHS * HDIM * sizeof(float));

    // ---- CSR build (bucketed counting sort)
    const int GB = (E + EPB - 1) / EPB;
    hipMemsetAsync(bcnt, 0, (size_t)NBUCK * sizeof(int), stream);
    k_bucket_count<<<GB, 256, 0, stream>>>(ei, bcnt, E);
    k_bucket_scan<<<1, 1024, 0, stream>>>(bcnt, bbase, bcur);
    k_bucket_scatter<<<GB, 256, 0, stream>>>(ei, bcur, bpack, E);
    k_bucket_sort<<<NBUCK, 256, 0, stream>>>(bpack, bbase, csr_src, row_ptr, N);

    // ---- weight prep + x cast
    k_cast_x<<<(N * 128 / 4 + 255) / 256, 256, 0, stream>>>(x, xh, N * 128 / 4);
    const float* ws_[6] = {cw1[0], cw2[0], cw1[1], cw2[1], cw1[2], cw2[2]};
    const int    wk_[6] = {128, 256, 256, 256, 256, 256};
    for (int i = 0; i < 6; ++i)
        k_prep_w<<<dim3(wk_[i] / 32, 8), 256, 0, stream>>>(ws_[i], wt[i], wk_[i]);

    const int agg_grid = (N + 3) / 4;
    const dim3 gemm_grid((N + 127) / 128, 2);

    // ---- layer 1
    k_aggregate_f16<128><<<agg_grid, 256, 0, stream>>>(xh, row_ptr, csr_src, nullptr, B0, N);
    k_gemm_mfma<128, false><<<gemm_grid, 256, 0, stream>>>(B0, wt[0], cb1[0], B1, nullptr, N);
    hipMemsetAsync(stats, 0, 2 * HDIM * sizeof(float), stream);
    k_gemm_mfma<256, true><<<gemm_grid, 256, 0, stream>>>(B1, wt[1], cb2[0], B2, stats, N);
    k_bn_finalize<<<1, 256, 0, stream>>>(stats, cg[0], cbe[0], st, N);

    // ---- layer 2 (layer-1 BN folded into aggregation)
    k_aggregate_f16<256><<<agg_grid, 256, 0, stream>>>(B2, row_ptr, csr_src, st, B0, N);
    k_gemm_mfma<256, false><<<gemm_grid, 256, 0, stream>>>(B0, wt[2], cb1[1], B1, nullptr, N);
    hipMemsetAsync(stats, 0, 2 * HDIM * sizeof(float), stream);
    k_gemm_mfma<256, true><<<gemm_grid, 256, 0, stream>>>(B1, wt[3], cb2[1], B0, stats, N);
    k_bn_finalize<<<1, 256, 0, stream>>>(stats, cg[1], cbe[1], st, N);

    // ---- layer 3
    k_aggregate_f16<256><<<agg_grid, 256, 0, stream>>>(B0, row_ptr, csr_src, st, B1, N);
    k_gemm_mfma<256, false><<<gemm_grid, 256, 0, stream>>>(B1, wt[4], cb1[2], B2, nullptr, N);
    hipMemsetAsync(stats, 0, 2 * HDIM * sizeof(float), stream);
    k_gemm_mfma<256, true><<<gemm_grid, 256, 0, stream>>>(B2, wt[5], cb2[2], B1, stats, N);
    k_bn_finalize<<<1, 256, 0, stream>>>(stats, cg[2], cbe[2], st, N);

    // ---- pool (layer-3 BN folded) + head
    hipMemsetAsync(pooled, 0, (size_t)N_GRAPHS * HDIM * sizeof(float), stream);
    k_pool_f16<<<(N + 127) / 128, 128, 0, stream>>>(B1, batch, st, pooled, N);
    k_head<<<N_GRAPHS, 256, 0, stream>>>(pooled, l1w, l1b, l2w, l2b, out);
}